// Round 8
// baseline (277.655 us; speedup 1.0000x reference)
//
#include <hip/hip_runtime.h>

#define Hh 384
#define Ww 384
#define NPX (Hh * Ww)

#define TW 64
#define TH 32
#define NTX 6
#define NTILES 72
#define FHH 58           // feat tile rows (TH + 26)
#define FHW 90           // feat tile cols (TW + 26)
#define OG 64            // offset groups per tile
#define NBLK 768
#define IPB 6            // items per block (NTILES*OG/NBLK)
#define VMAX 12
#define CSW 74           // cs row stride in f32 (72 + 2 pad; even -> rows 8B-aligned)
#define ROWA (FHW * 4)   // 360 B per sfA row (half2 c0c1)
// sfB row stride = ROWA/2 (half c2)

typedef _Float16 half_t;
typedef _Float16 __attribute__((ext_vector_type(2))) half2_t;
typedef _Float16 __attribute__((ext_vector_type(4))) half4_t;

__device__ __forceinline__ int iclampi(int v) { return v < 0 ? 0 : (v > 383 ? 383 : v); }

__device__ __forceinline__ half2_t u2h(unsigned u) {
    union { unsigned u; half2_t h; } c; c.u = u; return c.h;
}
__device__ __forceinline__ float fdot2u(unsigned a, half2_t w, float c) {
    return __builtin_amdgcn_fdot2(u2h(a), w, c, false);
}
// ||a-b||^2 for SoA pixels: (c0,c1) packed in u32, c2 as half.
// Value-identical to the old half4 form: f32 dot accumulate + exact f16->f32 cvt.
__device__ __forceinline__ float d2soa(unsigned aA, half_t aB, unsigned bA, half_t bB) {
    half2_t d01 = u2h(aA) - u2h(bA);
    half_t dc2 = aB - bB;
    float c2 = (float)dc2 * (float)dc2;
    return __builtin_amdgcn_fdot2(d01, d01, c2, false);
}

#if __has_builtin(__builtin_amdgcn_exp2f)
__device__ __forceinline__ float exp2fast(float x) { return __builtin_amdgcn_exp2f(x); }
#else
__device__ __forceinline__ float exp2fast(float x) { return __expf(x * 0.69314718055994531f); }
#endif

#define LOG2E 1.4426950408889634f

// ---------------- Kernel A: feature conv 7x7 + (block 0) weight pack / uniform detect ----------------
__global__ __launch_bounds__(256) void k_feat(const float* __restrict__ x,
                                              const float* __restrict__ ff,
                                              const float* __restrict__ pf,
                                              float* __restrict__ feat,
                                              unsigned* __restrict__ wpg) {
    int idx = blockIdx.x * 256 + threadIdx.x;
    // NPX == 576*256 exactly: no early-return; block 0 can barrier safely.
    int py = idx / Ww, px = idx % Ww;
    float a0 = 0.f, a1 = 0.f, a2 = 0.f;
    for (int i = 0; i < 7; ++i) {
        int yy = iclampi(py + i - 3);
        for (int j = 0; j < 7; ++j) {
            int xx = iclampi(px + j - 3);
            const float* xp = x + (yy * Ww + xx) * 3;
            const float* fp = ff + (i * 7 + j) * 9;
            float v0 = xp[0], v1 = xp[1], v2 = xp[2];
            a0 += v0 * fp[0] + v1 * fp[3] + v2 * fp[6];
            a1 += v0 * fp[1] + v1 * fp[4] + v2 * fp[7];
            a2 += v0 * fp[2] + v1 * fp[5] + v2 * fp[8];
        }
    }
    float* o = feat + idx * 3;
    o[0] = a0; o[1] = a1; o[2] = a2;

    if (blockIdx.x == 0) {
        __shared__ int oks[2];
        int t = threadIdx.x;
        if (t < 54) {
            int i = t / 6, sl = t % 6;
            float a = 0.f, b = 0.f;
            if (sl < 4)      { a = pf[i * 9 + 2 * sl]; b = pf[i * 9 + 2 * sl + 1]; }
            else if (sl == 4){ a = pf[i * 9 + 8]; b = 0.f; }
            else             { a = 0.f; b = pf[i * 9 + 8]; }
            half2_t h = { (half_t)a, (half_t)b };
            union { half2_t h; unsigned u; } c; c.h = h;
            wpg[t] = c.u;
        }
        bool ok = true;
        if (t < 81) ok = (pf[t] == pf[0]);
        unsigned long long bal = __ballot(ok);
        if (t < 128 && (t & 63) == 0) oks[t >> 6] = (~bal) == 0ULL;
        __syncthreads();
        if (t == 0) wpg[63] = (oks[0] && oks[1]) ? 1u : 0u;
    }
}

// ---------------- Kernel B: merged NLM (box fast path / general fallback) ----------------
// SoA feature tile: sfA = (c0,c1) half2 (4 B/px), sfB = c2 half (2 B/px).
// LDS raw = 20880 + 10440 + 9472 = 40792 -> 40960 rounded -> 4 blocks/CU.
// cs stage wave-aligned (216 act threads); pd stage (ty,tx) as before.
__global__ __launch_bounds__(256, 4) void k_nlm(const float* __restrict__ x,
                                                const float* __restrict__ feat,
                                                const unsigned* __restrict__ wpg,
                                                const float* __restrict__ pf,
                                                const float* __restrict__ inv_sigma,
                                                half4_t* __restrict__ part) {
    __shared__ __align__(16) unsigned sfA[FHH * FHW];   // 20880 B
    __shared__ __align__(16) half_t   sfB[FHH * FHW];   // 10440 B
    __shared__ __align__(16) union {
        float cs[32 * CSW];               // box path, 9472 B
        half_t d2g[40 * 72];              // gen path, 5760 B
    } su;

    const int b = blockIdx.x, tid = threadIdx.x;
    const int tx = tid & 7, ty = tid >> 3;

    if (wpg[63] != 0u) {
        // ---------------- BOX path ----------------
        float* s_cs = su.cs;
        const float mExp2 = -pf[0] * inv_sigma[0] * LOG2E;   // exp2-folded

        const int lane = tid & 63, wv = tid >> 6;
        const int band = (wv < 3) ? wv : (lane >> 3);
        const int c72  = (wv < 3) ? lane : (64 + (lane & 7));
        const int act  = (wv < 3) | (lane < 24);
        const int r0 = band * 12;
        const int nrows = (band < 2) ? 20 : 16;

        float num0[8], num1[8], num2[8], den[8];
        unsigned bbA[20]; half_t bbB[20];   // base-pixel features (register cache)
        unsigned cbyP[10];                  // packed u16 pairs: clamped base-row byte offs (plane A)
        int ccs = 0;

        float* cswb = s_cs + r0 * CSW + c72;
        const float* csr = s_cs + ty * CSW + 8 * tx;

        int cur_t = -1, oyt = 0, oxt = 0, vslot = 0, xbase = 0;

        for (int it = b * IPB; it < b * IPB + IPB; ++it) {
            int t = it >> 6;
            int g = it & (OG - 1);

            if (t != cur_t) {
                if (cur_t >= 0) {
#pragma unroll
                    for (int k = 0; k < 8; ++k) {
                        int px = (oyt + ty) * Ww + oxt + 8 * tx + k;
                        half4_t h = { (half_t)num0[k], (half_t)num1[k], (half_t)num2[k], (half_t)den[k] };
                        part[(size_t)vslot * NPX + px] = h;
                    }
                }
                cur_t = t;
                int tyi = t / NTX;
                oyt = tyi * TH; oxt = (t - tyi * NTX) * TW;
                vslot = b - (OG * t) / IPB;
                xbase = ((oyt + ty) * Ww + oxt + 8 * tx) * 3;

                __syncthreads();    // prior tile's LDS reads complete
                for (int e = tid; e < FHH * FHW; e += 256) {
                    int ly = e / FHW, lx = e - ly * FHW;
                    int gy = iclampi(oyt - 13 + ly), gx = iclampi(oxt - 13 + lx);
                    const float* fp = feat + (gy * Ww + gx) * 3;
                    half2_t h01 = { (half_t)fp[0], (half_t)fp[1] };
                    union { half2_t h; unsigned u; } c; c.h = h01;
                    sfA[e] = c.u;
                    sfB[e] = (half_t)fp[2];
                }
                __syncthreads();

                if (act) {
                    ccs = iclampi(oxt + c72 - 4) - oxt + 13;   // clamped base col index
#pragma unroll
                    for (int i = 0; i < 20; i += 2) {
                        int cA = (iclampi(oyt + r0 + i - 4) - oyt + 13) * ROWA;
                        int cB = (iclampi(oyt + r0 + i - 3) - oyt + 13) * ROWA;
                        cbyP[i >> 1] = (unsigned)cA | ((unsigned)cB << 16);
                        bbA[i]     = *(const unsigned*)((const char*)sfA + cA + ccs * 4);
                        bbB[i]     = *(const half_t*)((const char*)sfB + (cA >> 1) + ccs * 2);
                        bbA[i + 1] = *(const unsigned*)((const char*)sfA + cB + ccs * 4);
                        bbB[i + 1] = *(const half_t*)((const char*)sfB + (cB >> 1) + ccs * 2);
                    }
                }
#pragma unroll
                for (int k = 0; k < 8; ++k) { num0[k] = 0.f; num1[k] = 0.f; num2[k] = 0.f; den[k] = 0.f; }
            }

            int o0 = (361 * g) / OG, o1 = (361 * (g + 1)) / OG;
            for (int o = o0; o < o1; ++o) {
                int oy = o / 19, ox = o - oy * 19;
                int offy = oy - 9, offx = ox - 9;

                __syncthreads();   // prior pd reads of s_cs done
                if (act) {
                    // comparand base: staging clamp supplies clamp(clamp(base)+off)
                    const char* colpA = (const char*)sfA + (ccs + offx) * 4 + offy * ROWA;
                    const char* colpB = (const char*)sfB + (ccs + offx) * 2 + offy * (ROWA / 2);
                    float ring[9]; float s = 0.f;
#pragma unroll
                    for (int i = 0; i < 20; ++i) {
                        int cb = (i & 1) ? (int)(cbyP[i >> 1] >> 16) : (int)(cbyP[i >> 1] & 0xffffu);
                        unsigned qa = *(const unsigned*)(colpA + cb);
                        half_t  qb = *(const half_t*)(colpB + (cb >> 1));
                        float d2v = d2soa(qa, qb, bbA[i], bbB[i]);
                        ring[i % 9] = d2v;
                        s += d2v;
                        if (i >= 8) {
                            if (i < nrows) cswb[(i - 8) * CSW] = s;
                            s -= ring[(i - 8) % 9];
                        }
                    }
                }
                __syncthreads();

                // pd stage: sliding 9-wide row sums over cs (rows 8B-aligned at CSW=74)
                float2 q0 = *(const float2*)(csr);
                float2 q1 = *(const float2*)(csr + 2);
                float2 q2 = *(const float2*)(csr + 4);
                float2 q3 = *(const float2*)(csr + 6);
                float2 q4 = *(const float2*)(csr + 8);
                float2 q5 = *(const float2*)(csr + 10);
                float2 q6 = *(const float2*)(csr + 12);
                float2 q7 = *(const float2*)(csr + 14);
                float w_[16] = { q0.x, q0.y, q1.x, q1.y, q2.x, q2.y, q3.x, q3.y,
                                 q4.x, q4.y, q5.x, q5.y, q6.x, q6.y, q7.x, q7.y };
                float pdv[8];
                pdv[0] = w_[0] + w_[1] + w_[2] + w_[3] + w_[4] + w_[5] + w_[6] + w_[7] + w_[8];
#pragma unroll
                for (int k = 1; k < 8; ++k) pdv[k] = pdv[k - 1] - w_[k - 1] + w_[k + 8];

                // wave-uniform: no clamping needed iff the whole tile+offset window
                // stays on-image.
                int safe = ((unsigned)(oyt + offy) <= (unsigned)(Hh - TH)) &
                           ((unsigned)(oxt + offx) <= (unsigned)(Ww - TW));
                if (safe) {
                    const float* xp = x + xbase + (offy * Ww + offx) * 3;
#pragma unroll
                    for (int k = 0; k < 8; ++k) {
                        float wgt = exp2fast(pdv[k] * mExp2);
                        num0[k] += wgt * xp[3 * k + 0];
                        num1[k] += wgt * xp[3 * k + 1];
                        num2[k] += wgt * xp[3 * k + 2];
                        den[k] += wgt;
                    }
                } else {
                    int ry = iclampi(oyt + ty + offy);
                    const float* xr = x + ry * (Ww * 3);
#pragma unroll
                    for (int k = 0; k < 8; ++k) {
                        float wgt = exp2fast(pdv[k] * mExp2);
                        int gx = iclampi(oxt + 8 * tx + k + offx);
                        const float* xq = xr + gx * 3;
                        num0[k] += wgt * xq[0];
                        num1[k] += wgt * xq[1];
                        num2[k] += wgt * xq[2];
                        den[k] += wgt;
                    }
                }
            }
        }

        // final flush
#pragma unroll
        for (int k = 0; k < 8; ++k) {
            int px = (oyt + ty) * Ww + oxt + 8 * tx + k;
            half4_t h = { (half_t)num0[k], (half_t)num1[k], (half_t)num2[k], (half_t)den[k] };
            part[(size_t)vslot * NPX + px] = h;
        }
    } else {
        // ---------------- GENERAL path (arbitrary patch filter) ----------------
        half_t* sd2g = su.d2g;
        const float isig2 = inv_sigma[0] * LOG2E;

        float num0[8], num1[8], num2[8], den[8];
        int bidx[12]; unsigned fbA[12]; half_t fbB[12];
        int cur_t = -1, oyt = 0, oxt = 0, vslot = 0;

        for (int it = b * IPB; it < b * IPB + IPB; ++it) {
            int t = it >> 6;
            int g = it & (OG - 1);

            if (t != cur_t) {
                if (cur_t >= 0) {
#pragma unroll
                    for (int k = 0; k < 8; ++k) {
                        int px = (oyt + ty) * Ww + oxt + 8 * tx + k;
                        half4_t h = { (half_t)num0[k], (half_t)num1[k], (half_t)num2[k], (half_t)den[k] };
                        part[(size_t)vslot * NPX + px] = h;
                    }
                }
                cur_t = t;
                int tyi = t / NTX;
                oyt = tyi * TH; oxt = (t - tyi * NTX) * TW;
                vslot = b - (OG * t) / IPB;

                __syncthreads();
                for (int e = tid; e < FHH * FHW; e += 256) {
                    int ly = e / FHW, lx = e - ly * FHW;
                    int gy = iclampi(oyt - 13 + ly), gx = iclampi(oxt - 13 + lx);
                    const float* fp = feat + (gy * Ww + gx) * 3;
                    half2_t h01 = { (half_t)fp[0], (half_t)fp[1] };
                    union { half2_t h; unsigned u; } c; c.h = h01;
                    sfA[e] = c.u;
                    sfB[e] = (half_t)fp[2];
                }
                __syncthreads();

#pragma unroll
                for (int s = 0; s < 12; ++s) {
                    int e = tid + s * 256;
                    if (e < 40 * 72) {
                        int r = e / 72, cc = e - r * 72;
                        int ri = iclampi(oyt - 4 + r) - oyt + 13;
                        int ci = iclampi(oxt - 4 + cc) - oxt + 13;
                        bidx[s] = ri * FHW + ci;
                        fbA[s] = sfA[bidx[s]];
                        fbB[s] = sfB[bidx[s]];
                    } else { bidx[s] = 0; fbA[s] = 0; fbB[s] = (half_t)0.f; }
                }
#pragma unroll
                for (int k = 0; k < 8; ++k) { num0[k] = 0.f; num1[k] = 0.f; num2[k] = 0.f; den[k] = 0.f; }
            }

            int o0 = (361 * g) / OG, o1 = (361 * (g + 1)) / OG;
            for (int o = o0; o < o1; ++o) {
                int oy = o / 19, ox = o - oy * 19;
                int offy = oy - 9, offx = ox - 9;
                int du = offy * FHW + offx;

                __syncthreads();
#pragma unroll
                for (int s = 0; s < 12; ++s) {
                    int e = tid + s * 256;
                    if (e < 40 * 72) {
                        unsigned qa = sfA[bidx[s] + du];
                        half_t  qb = sfB[bidx[s] + du];
                        sd2g[e] = (half_t)d2soa(qa, qb, fbA[s], fbB[s]);
                    }
                }
                __syncthreads();

                float pd[8];
#pragma unroll
                for (int k = 0; k < 8; ++k) pd[k] = 0.f;
#pragma unroll
                for (int i = 0; i < 9; ++i) {
                    const uint4* rp = (const uint4*)&sd2g[(ty + i) * 72 + 8 * tx];
                    uint4 Aq = rp[0], Bq = rp[1];
                    unsigned rr[8] = { Aq.x, Aq.y, Aq.z, Aq.w, Bq.x, Bq.y, Bq.z, Bq.w };
                    unsigned sh[7];
#pragma unroll
                    for (int m = 0; m < 7; ++m) sh[m] = __builtin_amdgcn_alignbit(rr[m + 1], rr[m], 16);
                    half2_t w0 = u2h(wpg[i * 6 + 0]), w1 = u2h(wpg[i * 6 + 1]);
                    half2_t w2 = u2h(wpg[i * 6 + 2]), w3 = u2h(wpg[i * 6 + 3]);
                    half2_t wtE = u2h(wpg[i * 6 + 4]), wtO = u2h(wpg[i * 6 + 5]);
#pragma unroll
                    for (int k = 0; k < 8; k += 2) {
                        int m = k >> 1;
                        float p = pd[k];
                        p = fdot2u(rr[m + 0], w0, p);
                        p = fdot2u(rr[m + 1], w1, p);
                        p = fdot2u(rr[m + 2], w2, p);
                        p = fdot2u(rr[m + 3], w3, p);
                        p = fdot2u(rr[m + 4], wtE, p);
                        pd[k] = p;
                        float q = pd[k + 1];
                        q = fdot2u(sh[m + 0], w0, q);
                        q = fdot2u(sh[m + 1], w1, q);
                        q = fdot2u(sh[m + 2], w2, q);
                        q = fdot2u(sh[m + 3], w3, q);
                        q = fdot2u(rr[m + 4], wtO, q);
                        pd[k + 1] = q;
                    }
                }

                int ry = iclampi(oyt + ty + offy);
                const float* xr = x + ry * (Ww * 3);
#pragma unroll
                for (int k = 0; k < 8; ++k) {
                    float wgt = exp2fast(-pd[k] * isig2);
                    int gx = iclampi(oxt + 8 * tx + k + offx);
                    const float* xq = xr + gx * 3;
                    num0[k] += wgt * xq[0];
                    num1[k] += wgt * xq[1];
                    num2[k] += wgt * xq[2];
                    den[k] += wgt;
                }
            }
        }

#pragma unroll
        for (int k = 0; k < 8; ++k) {
            int px = (oyt + ty) * Ww + oxt + 8 * tx + k;
            half4_t h = { (half_t)num0[k], (half_t)num1[k], (half_t)num2[k], (half_t)den[k] };
            part[(size_t)vslot * NPX + px] = h;
        }
    }
}

// ---------------- Kernel C: reduce visitor partials ----------------
__global__ __launch_bounds__(256) void k_reduce(const half4_t* __restrict__ part,
                                                float* __restrict__ out) {
    int px = blockIdx.x * 256 + threadIdx.x;
    if (px >= NPX) return;
    int y = px / Ww, xx = px - y * Ww;
    int t = (y / TH) * NTX + xx / TW;
    int bfirst = (OG * t) / IPB;
    int blast = (OG * t + OG - 1) / IPB;
    int nvis = blast - bfirst + 1;
    float n0 = 0.f, n1 = 0.f, n2 = 0.f, dd = 0.f;
#pragma unroll
    for (int v = 0; v < VMAX; ++v) {
        if (v < nvis) {
            half4_t h = part[(size_t)v * NPX + px];
            n0 += (float)h.x; n1 += (float)h.y; n2 += (float)h.z; dd += (float)h.w;
        }
    }
    float inv = 1.f / dd;
    out[px * 3 + 0] = n0 * inv;
    out[px * 3 + 1] = n1 * inv;
    out[px * 3 + 2] = n2 * inv;
}

extern "C" void kernel_launch(void* const* d_in, const int* in_sizes, int n_in,
                              void* d_out, int out_size, void* d_ws, size_t ws_size,
                              hipStream_t stream) {
    const float* x    = (const float*)d_in[0];
    const float* ff   = (const float*)d_in[1];
    const float* pf   = (const float*)d_in[2];
    const float* isig = (const float*)d_in[3];
    float* out = (float*)d_out;

    // ws layout: [feat NPX*3 f32][wpg+flag 256B][part VMAX*NPX half4]
    float* feat   = (float*)d_ws;
    unsigned* wpg = (unsigned*)((char*)d_ws + (size_t)NPX * 3 * 4);
    half4_t* part = (half4_t*)((char*)d_ws + (size_t)NPX * 3 * 4 + 256);

    k_feat<<<dim3(NPX / 256), 256, 0, stream>>>(x, ff, pf, feat, wpg);
    k_nlm<<<dim3(NBLK), 256, 0, stream>>>(x, feat, wpg, pf, isig, part);
    k_reduce<<<dim3((NPX + 255) / 256), 256, 0, stream>>>(part, out);
}

// Round 9
// 112.509 us; speedup vs baseline: 2.4679x; 2.4679x over previous
//
#include <hip/hip_runtime.h>

#define Hh 384
#define Ww 384
#define NPX (Hh * Ww)

#define TW 64
#define TH 32
#define NTX 6
#define NTILES 72
#define FHH 58           // feat tile rows (TH + 26)
#define FHW 90           // feat tile cols (TW + 26)
#define OG 64            // offset groups per tile
#define NBLK 768
#define IPB 6            // items per block (NTILES*OG/NBLK)
#define VMAX 12
#define CSW 74           // cs row stride in f32 (72 + 2 pad; even -> rows 8B-aligned)
#define ROWA (FHW * 4)   // 360 B per sfA row (half2 c0c1)
// sfB row stride = ROWA/2 (half c2)

typedef _Float16 half_t;
typedef _Float16 __attribute__((ext_vector_type(2))) half2_t;
typedef _Float16 __attribute__((ext_vector_type(4))) half4_t;

__device__ __forceinline__ int iclampi(int v) { return v < 0 ? 0 : (v > 383 ? 383 : v); }

__device__ __forceinline__ half2_t u2h(unsigned u) {
    union { unsigned u; half2_t h; } c; c.u = u; return c.h;
}
__device__ __forceinline__ float fdot2u(unsigned a, half2_t w, float c) {
    return __builtin_amdgcn_fdot2(u2h(a), w, c, false);
}
// ||a-b||^2 for SoA pixels: (c0,c1) packed in u32, c2 as half.
// Value-identical to the old half4 form: f32 dot accumulate + exact f16->f32 cvt.
__device__ __forceinline__ float d2soa(unsigned aA, half_t aB, unsigned bA, half_t bB) {
    half2_t d01 = u2h(aA) - u2h(bA);
    half_t dc2 = aB - bB;
    float c2 = (float)dc2 * (float)dc2;
    return __builtin_amdgcn_fdot2(d01, d01, c2, false);
}

#if __has_builtin(__builtin_amdgcn_exp2f)
__device__ __forceinline__ float exp2fast(float x) { return __builtin_amdgcn_exp2f(x); }
#else
__device__ __forceinline__ float exp2fast(float x) { return __expf(x * 0.69314718055994531f); }
#endif

#define LOG2E 1.4426950408889634f

// ---------------- Kernel A: feature conv 7x7 + (block 0) weight pack / uniform detect ----------------
__global__ __launch_bounds__(256) void k_feat(const float* __restrict__ x,
                                              const float* __restrict__ ff,
                                              const float* __restrict__ pf,
                                              float* __restrict__ feat,
                                              unsigned* __restrict__ wpg) {
    int idx = blockIdx.x * 256 + threadIdx.x;
    // NPX == 576*256 exactly: no early-return; block 0 can barrier safely.
    int py = idx / Ww, px = idx % Ww;
    float a0 = 0.f, a1 = 0.f, a2 = 0.f;
    for (int i = 0; i < 7; ++i) {
        int yy = iclampi(py + i - 3);
        for (int j = 0; j < 7; ++j) {
            int xx = iclampi(px + j - 3);
            const float* xp = x + (yy * Ww + xx) * 3;
            const float* fp = ff + (i * 7 + j) * 9;
            float v0 = xp[0], v1 = xp[1], v2 = xp[2];
            a0 += v0 * fp[0] + v1 * fp[3] + v2 * fp[6];
            a1 += v0 * fp[1] + v1 * fp[4] + v2 * fp[7];
            a2 += v0 * fp[2] + v1 * fp[5] + v2 * fp[8];
        }
    }
    float* o = feat + idx * 3;
    o[0] = a0; o[1] = a1; o[2] = a2;

    if (blockIdx.x == 0) {
        __shared__ int oks[2];
        int t = threadIdx.x;
        if (t < 54) {
            int i = t / 6, sl = t % 6;
            float a = 0.f, b = 0.f;
            if (sl < 4)      { a = pf[i * 9 + 2 * sl]; b = pf[i * 9 + 2 * sl + 1]; }
            else if (sl == 4){ a = pf[i * 9 + 8]; b = 0.f; }
            else             { a = 0.f; b = pf[i * 9 + 8]; }
            half2_t h = { (half_t)a, (half_t)b };
            union { half2_t h; unsigned u; } c; c.h = h;
            wpg[t] = c.u;
        }
        bool ok = true;
        if (t < 81) ok = (pf[t] == pf[0]);
        unsigned long long bal = __ballot(ok);
        if (t < 128 && (t & 63) == 0) oks[t >> 6] = (~bal) == 0ULL;
        __syncthreads();
        if (t == 0) wpg[63] = (oks[0] && oks[1]) ? 1u : 0u;
    }
}

// ---------------- Kernel B: merged NLM (box fast path / general fallback) ----------------
// SoA feature tile: sfA = (c0,c1) half2 (4 B/px), sfB = c2 half (2 B/px).
// LDS raw = 20880 + 10440 + 9472 = 40792 -> 40960 alloc -> 4 blocks/CU possible.
// launch_bounds kept at (256,3): min-waves 4 made the allocator spill to the
// 64-VGPR / 8-waves-per-EU budget (R8: FETCH 110MB, 277us). With (256,3) the
// allocator allocates its natural ~84-100 VGPR (<=128), and the HW scheduler
// still co-resides 4 blocks since LDS 4x40960 = 160KB exactly and VGPR<=128
// permits 16 waves/CU.
__global__ __launch_bounds__(256, 3) void k_nlm(const float* __restrict__ x,
                                                const float* __restrict__ feat,
                                                const unsigned* __restrict__ wpg,
                                                const float* __restrict__ pf,
                                                const float* __restrict__ inv_sigma,
                                                half4_t* __restrict__ part) {
    __shared__ __align__(16) unsigned sfA[FHH * FHW];   // 20880 B
    __shared__ __align__(16) half_t   sfB[FHH * FHW];   // 10440 B
    __shared__ __align__(16) union {
        float cs[32 * CSW];               // box path, 9472 B
        half_t d2g[40 * 72];              // gen path, 5760 B
    } su;

    const int b = blockIdx.x, tid = threadIdx.x;
    const int tx = tid & 7, ty = tid >> 3;

    if (wpg[63] != 0u) {
        // ---------------- BOX path ----------------
        float* s_cs = su.cs;
        const float mExp2 = -pf[0] * inv_sigma[0] * LOG2E;   // exp2-folded

        const int lane = tid & 63, wv = tid >> 6;
        const int band = (wv < 3) ? wv : (lane >> 3);
        const int c72  = (wv < 3) ? lane : (64 + (lane & 7));
        const int act  = (wv < 3) | (lane < 24);
        const int r0 = band * 12;
        const int nrows = (band < 2) ? 20 : 16;

        float num0[8], num1[8], num2[8], den[8];
        unsigned bbA[20]; half_t bbB[20];   // base-pixel features (register cache)
        unsigned cbyP[10];                  // packed u16 pairs: clamped base-row byte offs (plane A)
        int ccs = 0;

        float* cswb = s_cs + r0 * CSW + c72;
        const float* csr = s_cs + ty * CSW + 8 * tx;

        int cur_t = -1, oyt = 0, oxt = 0, vslot = 0, xbase = 0;

        for (int it = b * IPB; it < b * IPB + IPB; ++it) {
            int t = it >> 6;
            int g = it & (OG - 1);

            if (t != cur_t) {
                if (cur_t >= 0) {
#pragma unroll
                    for (int k = 0; k < 8; ++k) {
                        int px = (oyt + ty) * Ww + oxt + 8 * tx + k;
                        half4_t h = { (half_t)num0[k], (half_t)num1[k], (half_t)num2[k], (half_t)den[k] };
                        part[(size_t)vslot * NPX + px] = h;
                    }
                }
                cur_t = t;
                int tyi = t / NTX;
                oyt = tyi * TH; oxt = (t - tyi * NTX) * TW;
                vslot = b - (OG * t) / IPB;
                xbase = ((oyt + ty) * Ww + oxt + 8 * tx) * 3;

                __syncthreads();    // prior tile's LDS reads complete
                for (int e = tid; e < FHH * FHW; e += 256) {
                    int ly = e / FHW, lx = e - ly * FHW;
                    int gy = iclampi(oyt - 13 + ly), gx = iclampi(oxt - 13 + lx);
                    const float* fp = feat + (gy * Ww + gx) * 3;
                    half2_t h01 = { (half_t)fp[0], (half_t)fp[1] };
                    union { half2_t h; unsigned u; } c; c.h = h01;
                    sfA[e] = c.u;
                    sfB[e] = (half_t)fp[2];
                }
                __syncthreads();

                if (act) {
                    ccs = iclampi(oxt + c72 - 4) - oxt + 13;   // clamped base col index
#pragma unroll
                    for (int i = 0; i < 20; i += 2) {
                        int cA = (iclampi(oyt + r0 + i - 4) - oyt + 13) * ROWA;
                        int cB = (iclampi(oyt + r0 + i - 3) - oyt + 13) * ROWA;
                        cbyP[i >> 1] = (unsigned)cA | ((unsigned)cB << 16);
                        bbA[i]     = *(const unsigned*)((const char*)sfA + cA + ccs * 4);
                        bbB[i]     = *(const half_t*)((const char*)sfB + (cA >> 1) + ccs * 2);
                        bbA[i + 1] = *(const unsigned*)((const char*)sfA + cB + ccs * 4);
                        bbB[i + 1] = *(const half_t*)((const char*)sfB + (cB >> 1) + ccs * 2);
                    }
                }
#pragma unroll
                for (int k = 0; k < 8; ++k) { num0[k] = 0.f; num1[k] = 0.f; num2[k] = 0.f; den[k] = 0.f; }
            }

            int o0 = (361 * g) / OG, o1 = (361 * (g + 1)) / OG;
            for (int o = o0; o < o1; ++o) {
                int oy = o / 19, ox = o - oy * 19;
                int offy = oy - 9, offx = ox - 9;

                __syncthreads();   // prior pd reads of s_cs done
                if (act) {
                    // comparand base: staging clamp supplies clamp(clamp(base)+off)
                    const char* colpA = (const char*)sfA + (ccs + offx) * 4 + offy * ROWA;
                    const char* colpB = (const char*)sfB + (ccs + offx) * 2 + offy * (ROWA / 2);
                    float ring[9]; float s = 0.f;
#pragma unroll
                    for (int i = 0; i < 20; ++i) {
                        int cb = (i & 1) ? (int)(cbyP[i >> 1] >> 16) : (int)(cbyP[i >> 1] & 0xffffu);
                        unsigned qa = *(const unsigned*)(colpA + cb);
                        half_t  qb = *(const half_t*)(colpB + (cb >> 1));
                        float d2v = d2soa(qa, qb, bbA[i], bbB[i]);
                        ring[i % 9] = d2v;
                        s += d2v;
                        if (i >= 8) {
                            if (i < nrows) cswb[(i - 8) * CSW] = s;
                            s -= ring[(i - 8) % 9];
                        }
                    }
                }
                __syncthreads();

                // pd stage: sliding 9-wide row sums over cs (rows 8B-aligned at CSW=74)
                float2 q0 = *(const float2*)(csr);
                float2 q1 = *(const float2*)(csr + 2);
                float2 q2 = *(const float2*)(csr + 4);
                float2 q3 = *(const float2*)(csr + 6);
                float2 q4 = *(const float2*)(csr + 8);
                float2 q5 = *(const float2*)(csr + 10);
                float2 q6 = *(const float2*)(csr + 12);
                float2 q7 = *(const float2*)(csr + 14);
                float w_[16] = { q0.x, q0.y, q1.x, q1.y, q2.x, q2.y, q3.x, q3.y,
                                 q4.x, q4.y, q5.x, q5.y, q6.x, q6.y, q7.x, q7.y };
                float pdv[8];
                pdv[0] = w_[0] + w_[1] + w_[2] + w_[3] + w_[4] + w_[5] + w_[6] + w_[7] + w_[8];
#pragma unroll
                for (int k = 1; k < 8; ++k) pdv[k] = pdv[k - 1] - w_[k - 1] + w_[k + 8];

                // wave-uniform: no clamping needed iff the whole tile+offset window
                // stays on-image.
                int safe = ((unsigned)(oyt + offy) <= (unsigned)(Hh - TH)) &
                           ((unsigned)(oxt + offx) <= (unsigned)(Ww - TW));
                if (safe) {
                    const float* xp = x + xbase + (offy * Ww + offx) * 3;
#pragma unroll
                    for (int k = 0; k < 8; ++k) {
                        float wgt = exp2fast(pdv[k] * mExp2);
                        num0[k] += wgt * xp[3 * k + 0];
                        num1[k] += wgt * xp[3 * k + 1];
                        num2[k] += wgt * xp[3 * k + 2];
                        den[k] += wgt;
                    }
                } else {
                    int ry = iclampi(oyt + ty + offy);
                    const float* xr = x + ry * (Ww * 3);
#pragma unroll
                    for (int k = 0; k < 8; ++k) {
                        float wgt = exp2fast(pdv[k] * mExp2);
                        int gx = iclampi(oxt + 8 * tx + k + offx);
                        const float* xq = xr + gx * 3;
                        num0[k] += wgt * xq[0];
                        num1[k] += wgt * xq[1];
                        num2[k] += wgt * xq[2];
                        den[k] += wgt;
                    }
                }
            }
        }

        // final flush
#pragma unroll
        for (int k = 0; k < 8; ++k) {
            int px = (oyt + ty) * Ww + oxt + 8 * tx + k;
            half4_t h = { (half_t)num0[k], (half_t)num1[k], (half_t)num2[k], (half_t)den[k] };
            part[(size_t)vslot * NPX + px] = h;
        }
    } else {
        // ---------------- GENERAL path (arbitrary patch filter) ----------------
        half_t* sd2g = su.d2g;
        const float isig2 = inv_sigma[0] * LOG2E;

        float num0[8], num1[8], num2[8], den[8];
        int bidx[12]; unsigned fbA[12]; half_t fbB[12];
        int cur_t = -1, oyt = 0, oxt = 0, vslot = 0;

        for (int it = b * IPB; it < b * IPB + IPB; ++it) {
            int t = it >> 6;
            int g = it & (OG - 1);

            if (t != cur_t) {
                if (cur_t >= 0) {
#pragma unroll
                    for (int k = 0; k < 8; ++k) {
                        int px = (oyt + ty) * Ww + oxt + 8 * tx + k;
                        half4_t h = { (half_t)num0[k], (half_t)num1[k], (half_t)num2[k], (half_t)den[k] };
                        part[(size_t)vslot * NPX + px] = h;
                    }
                }
                cur_t = t;
                int tyi = t / NTX;
                oyt = tyi * TH; oxt = (t - tyi * NTX) * TW;
                vslot = b - (OG * t) / IPB;

                __syncthreads();
                for (int e = tid; e < FHH * FHW; e += 256) {
                    int ly = e / FHW, lx = e - ly * FHW;
                    int gy = iclampi(oyt - 13 + ly), gx = iclampi(oxt - 13 + lx);
                    const float* fp = feat + (gy * Ww + gx) * 3;
                    half2_t h01 = { (half_t)fp[0], (half_t)fp[1] };
                    union { half2_t h; unsigned u; } c; c.h = h01;
                    sfA[e] = c.u;
                    sfB[e] = (half_t)fp[2];
                }
                __syncthreads();

#pragma unroll
                for (int s = 0; s < 12; ++s) {
                    int e = tid + s * 256;
                    if (e < 40 * 72) {
                        int r = e / 72, cc = e - r * 72;
                        int ri = iclampi(oyt - 4 + r) - oyt + 13;
                        int ci = iclampi(oxt - 4 + cc) - oxt + 13;
                        bidx[s] = ri * FHW + ci;
                        fbA[s] = sfA[bidx[s]];
                        fbB[s] = sfB[bidx[s]];
                    } else { bidx[s] = 0; fbA[s] = 0; fbB[s] = (half_t)0.f; }
                }
#pragma unroll
                for (int k = 0; k < 8; ++k) { num0[k] = 0.f; num1[k] = 0.f; num2[k] = 0.f; den[k] = 0.f; }
            }

            int o0 = (361 * g) / OG, o1 = (361 * (g + 1)) / OG;
            for (int o = o0; o < o1; ++o) {
                int oy = o / 19, ox = o - oy * 19;
                int offy = oy - 9, offx = ox - 9;
                int du = offy * FHW + offx;

                __syncthreads();
#pragma unroll
                for (int s = 0; s < 12; ++s) {
                    int e = tid + s * 256;
                    if (e < 40 * 72) {
                        unsigned qa = sfA[bidx[s] + du];
                        half_t  qb = sfB[bidx[s] + du];
                        sd2g[e] = (half_t)d2soa(qa, qb, fbA[s], fbB[s]);
                    }
                }
                __syncthreads();

                float pd[8];
#pragma unroll
                for (int k = 0; k < 8; ++k) pd[k] = 0.f;
#pragma unroll
                for (int i = 0; i < 9; ++i) {
                    const uint4* rp = (const uint4*)&sd2g[(ty + i) * 72 + 8 * tx];
                    uint4 Aq = rp[0], Bq = rp[1];
                    unsigned rr[8] = { Aq.x, Aq.y, Aq.z, Aq.w, Bq.x, Bq.y, Bq.z, Bq.w };
                    unsigned sh[7];
#pragma unroll
                    for (int m = 0; m < 7; ++m) sh[m] = __builtin_amdgcn_alignbit(rr[m + 1], rr[m], 16);
                    half2_t w0 = u2h(wpg[i * 6 + 0]), w1 = u2h(wpg[i * 6 + 1]);
                    half2_t w2 = u2h(wpg[i * 6 + 2]), w3 = u2h(wpg[i * 6 + 3]);
                    half2_t wtE = u2h(wpg[i * 6 + 4]), wtO = u2h(wpg[i * 6 + 5]);
#pragma unroll
                    for (int k = 0; k < 8; k += 2) {
                        int m = k >> 1;
                        float p = pd[k];
                        p = fdot2u(rr[m + 0], w0, p);
                        p = fdot2u(rr[m + 1], w1, p);
                        p = fdot2u(rr[m + 2], w2, p);
                        p = fdot2u(rr[m + 3], w3, p);
                        p = fdot2u(rr[m + 4], wtE, p);
                        pd[k] = p;
                        float q = pd[k + 1];
                        q = fdot2u(sh[m + 0], w0, q);
                        q = fdot2u(sh[m + 1], w1, q);
                        q = fdot2u(sh[m + 2], w2, q);
                        q = fdot2u(sh[m + 3], w3, q);
                        q = fdot2u(rr[m + 4], wtO, q);
                        pd[k + 1] = q;
                    }
                }

                int ry = iclampi(oyt + ty + offy);
                const float* xr = x + ry * (Ww * 3);
#pragma unroll
                for (int k = 0; k < 8; ++k) {
                    float wgt = exp2fast(-pd[k] * isig2);
                    int gx = iclampi(oxt + 8 * tx + k + offx);
                    const float* xq = xr + gx * 3;
                    num0[k] += wgt * xq[0];
                    num1[k] += wgt * xq[1];
                    num2[k] += wgt * xq[2];
                    den[k] += wgt;
                }
            }
        }

#pragma unroll
        for (int k = 0; k < 8; ++k) {
            int px = (oyt + ty) * Ww + oxt + 8 * tx + k;
            half4_t h = { (half_t)num0[k], (half_t)num1[k], (half_t)num2[k], (half_t)den[k] };
            part[(size_t)vslot * NPX + px] = h;
        }
    }
}

// ---------------- Kernel C: reduce visitor partials ----------------
__global__ __launch_bounds__(256) void k_reduce(const half4_t* __restrict__ part,
                                                float* __restrict__ out) {
    int px = blockIdx.x * 256 + threadIdx.x;
    if (px >= NPX) return;
    int y = px / Ww, xx = px - y * Ww;
    int t = (y / TH) * NTX + xx / TW;
    int bfirst = (OG * t) / IPB;
    int blast = (OG * t + OG - 1) / IPB;
    int nvis = blast - bfirst + 1;
    float n0 = 0.f, n1 = 0.f, n2 = 0.f, dd = 0.f;
#pragma unroll
    for (int v = 0; v < VMAX; ++v) {
        if (v < nvis) {
            half4_t h = part[(size_t)v * NPX + px];
            n0 += (float)h.x; n1 += (float)h.y; n2 += (float)h.z; dd += (float)h.w;
        }
    }
    float inv = 1.f / dd;
    out[px * 3 + 0] = n0 * inv;
    out[px * 3 + 1] = n1 * inv;
    out[px * 3 + 2] = n2 * inv;
}

extern "C" void kernel_launch(void* const* d_in, const int* in_sizes, int n_in,
                              void* d_out, int out_size, void* d_ws, size_t ws_size,
                              hipStream_t stream) {
    const float* x    = (const float*)d_in[0];
    const float* ff   = (const float*)d_in[1];
    const float* pf   = (const float*)d_in[2];
    const float* isig = (const float*)d_in[3];
    float* out = (float*)d_out;

    // ws layout: [feat NPX*3 f32][wpg+flag 256B][part VMAX*NPX half4]
    float* feat   = (float*)d_ws;
    unsigned* wpg = (unsigned*)((char*)d_ws + (size_t)NPX * 3 * 4);
    half4_t* part = (half4_t*)((char*)d_ws + (size_t)NPX * 3 * 4 + 256);

    k_feat<<<dim3(NPX / 256), 256, 0, stream>>>(x, ff, pf, feat, wpg);
    k_nlm<<<dim3(NBLK), 256, 0, stream>>>(x, feat, wpg, pf, isig, part);
    k_reduce<<<dim3((NPX + 255) / 256), 256, 0, stream>>>(part, out);
}

// Round 10
// 101.363 us; speedup vs baseline: 2.7392x; 1.1100x over previous
//
#include <hip/hip_runtime.h>

#define Hh 384
#define Ww 384
#define NPX (Hh * Ww)

#define TW 64
#define TH 32
#define NTX 6
#define NTILES 72
#define FHH 58           // feat tile rows (TH + 26)
#define FHW 90           // feat tile cols (TW + 26)
#define OG 64            // offset groups per tile
#define NBLK 768
#define IPB 6            // items per block (NTILES*OG/NBLK)
#define VMAX 12
#define CSW 76           // cs row stride in f32 (72 + 4 pad)
#define ROWB (FHW * 8)   // 720 bytes per sfT row (row-major half4)

typedef _Float16 half_t;
typedef _Float16 __attribute__((ext_vector_type(2))) half2_t;
typedef _Float16 __attribute__((ext_vector_type(4))) half4_t;

__device__ __forceinline__ int iclampi(int v) { return v < 0 ? 0 : (v > 383 ? 383 : v); }

__device__ __forceinline__ half2_t u2h(unsigned u) {
    union { unsigned u; half2_t h; } c; c.u = u; return c.h;
}
__device__ __forceinline__ float fdot2u(unsigned a, half2_t w, float c) {
    return __builtin_amdgcn_fdot2(u2h(a), w, c, false);
}
// ||a-b||^2 for half4 packed as (L,H) u32 pairs; .w lanes are 0 on both sides
__device__ __forceinline__ float d2u(unsigned aL, unsigned aH, unsigned bL, unsigned bH) {
    half2_t dl = u2h(aL) - u2h(bL);
    half2_t dh = u2h(aH) - u2h(bH);
    return __builtin_amdgcn_fdot2(dl, dl, __builtin_amdgcn_fdot2(dh, dh, 0.f, false), false);
}

#if __has_builtin(__builtin_amdgcn_exp2f)
__device__ __forceinline__ float exp2fast(float x) { return __builtin_amdgcn_exp2f(x); }
#else
__device__ __forceinline__ float exp2fast(float x) { return __expf(x * 0.69314718055994531f); }
#endif

#define LOG2E 1.4426950408889634f

// ---------------- Kernel A: feature conv 7x7 + (block 0) weight pack / uniform detect ----------------
__global__ __launch_bounds__(256) void k_feat(const float* __restrict__ x,
                                              const float* __restrict__ ff,
                                              const float* __restrict__ pf,
                                              float* __restrict__ feat,
                                              unsigned* __restrict__ wpg) {
    int idx = blockIdx.x * 256 + threadIdx.x;
    // NPX == 576*256 exactly: no early-return; block 0 can barrier safely.
    int py = idx / Ww, px = idx % Ww;
    float a0 = 0.f, a1 = 0.f, a2 = 0.f;
    for (int i = 0; i < 7; ++i) {
        int yy = iclampi(py + i - 3);
        for (int j = 0; j < 7; ++j) {
            int xx = iclampi(px + j - 3);
            const float* xp = x + (yy * Ww + xx) * 3;
            const float* fp = ff + (i * 7 + j) * 9;
            float v0 = xp[0], v1 = xp[1], v2 = xp[2];
            a0 += v0 * fp[0] + v1 * fp[3] + v2 * fp[6];
            a1 += v0 * fp[1] + v1 * fp[4] + v2 * fp[7];
            a2 += v0 * fp[2] + v1 * fp[5] + v2 * fp[8];
        }
    }
    float* o = feat + idx * 3;
    o[0] = a0; o[1] = a1; o[2] = a2;

    if (blockIdx.x == 0) {
        __shared__ int oks[2];
        int t = threadIdx.x;
        if (t < 54) {
            int i = t / 6, sl = t % 6;
            float a = 0.f, b = 0.f;
            if (sl < 4)      { a = pf[i * 9 + 2 * sl]; b = pf[i * 9 + 2 * sl + 1]; }
            else if (sl == 4){ a = pf[i * 9 + 8]; b = 0.f; }
            else             { a = 0.f; b = pf[i * 9 + 8]; }
            half2_t h = { (half_t)a, (half_t)b };
            union { half2_t h; unsigned u; } c; c.h = h;
            wpg[t] = c.u;
        }
        bool ok = true;
        if (t < 81) ok = (pf[t] == pf[0]);
        unsigned long long bal = __ballot(ok);
        if (t < 128 && (t & 63) == 0) oks[t >> 6] = (~bal) == 0ULL;
        __syncthreads();
        if (t == 0) wpg[63] = (oks[0] && oks[1]) ? 1u : 0u;
    }
}

// ---------------- Kernel B: merged NLM (box fast path / general fallback) ----------------
// Block-uniform branch on wpg[63]; barriers legal on both sides.
// BOX: 768 persistent blocks, 6 items; 256 threads.
//   cs stage wave-aligned (216 act threads): waves 0-2 own one band x cols 0-63;
//   wave 3 lanes 0-23 cover cols 64-71.
//   rowOK tiles (oyt in [4,344], 10/12 tile-rows): no base-row clamping ->
//   comparand addr = colp2 + i*ROWB compile-time immediate (no cbyP unpack).
//   pd stage: thread (ty = tid>>3, tx = tid&7) -> row ty, cols 8tx..8tx+7.
//   x-gather: per-offset wave-uniform `safe` test.
__global__ __launch_bounds__(256, 3) void k_nlm(const float* __restrict__ x,
                                                const float* __restrict__ feat,
                                                const unsigned* __restrict__ wpg,
                                                const float* __restrict__ pf,
                                                const float* __restrict__ inv_sigma,
                                                half4_t* __restrict__ part) {
    __shared__ half4_t sfT[FHH * FHW];    // row-major [row][col], 41760 B
    __shared__ union {
        float cs[32 * CSW];               // box path, 9728 B
        half_t d2g[40 * 72];              // gen path, 5760 B
    } su;

    const int b = blockIdx.x, tid = threadIdx.x;
    const int tx = tid & 7, ty = tid >> 3;

    if (wpg[63] != 0u) {
        // ---------------- BOX path ----------------
        float* s_cs = su.cs;
        const float mExp2 = -pf[0] * inv_sigma[0] * LOG2E;   // exp2-folded

        const int lane = tid & 63, wv = tid >> 6;
        const int band = (wv < 3) ? wv : (lane >> 3);
        const int c72  = (wv < 3) ? lane : (64 + (lane & 7));
        const int act  = (wv < 3) | (lane < 24);
        const int r0 = band * 12;
        const int nrows = (band < 2) ? 20 : 16;

        float num0[8], num1[8], num2[8], den[8];
        unsigned bbL[20], bbH[20];     // base-pixel features (register cache)
        unsigned cbyP[10];             // packed u16 pairs: clamped base-row byte offsets
        int ccs = 0;

        float* cswb = s_cs + r0 * CSW + c72;
        const float* csr = s_cs + ty * CSW + 8 * tx;

        int cur_t = -1, oyt = 0, oxt = 0, vslot = 0, rowOK = 0, xbase = 0;

        for (int it = b * IPB; it < b * IPB + IPB; ++it) {
            int t = it >> 6;
            int g = it & (OG - 1);

            if (t != cur_t) {
                if (cur_t >= 0) {
#pragma unroll
                    for (int k = 0; k < 8; ++k) {
                        int px = (oyt + ty) * Ww + oxt + 8 * tx + k;
                        half4_t h = { (half_t)num0[k], (half_t)num1[k], (half_t)num2[k], (half_t)den[k] };
                        part[(size_t)vslot * NPX + px] = h;
                    }
                }
                cur_t = t;
                int tyi = t / NTX;
                oyt = tyi * TH; oxt = (t - tyi * NTX) * TW;
                vslot = b - (OG * t) / IPB;
                rowOK = (oyt >= 4 && oyt <= 344);   // all base rows unclamped for every band
                xbase = ((oyt + ty) * Ww + oxt + 8 * tx) * 3;

                __syncthreads();    // prior tile's LDS reads complete
                for (int e = tid; e < FHH * FHW; e += 256) {
                    int ly = e / FHW, lx = e - ly * FHW;
                    int gy = iclampi(oyt - 13 + ly), gx = iclampi(oxt - 13 + lx);
                    const float* fp = feat + (gy * Ww + gx) * 3;
                    sfT[e] = half4_t{ (half_t)fp[0], (half_t)fp[1], (half_t)fp[2], (half_t)0.f };
                }
                __syncthreads();

                if (act) {
                    ccs = iclampi(oxt + c72 - 4) - oxt + 13;   // clamped base col index
#pragma unroll
                    for (int i = 0; i < 20; i += 2) {
                        int cA = (iclampi(oyt + r0 + i - 4) - oyt + 13) * ROWB;
                        int cB = (iclampi(oyt + r0 + i - 3) - oyt + 13) * ROWB;
                        cbyP[i >> 1] = (unsigned)cA | ((unsigned)cB << 16);
                        uint2 qA = *(const uint2*)((const char*)sfT + cA + ccs * 8);
                        uint2 qB = *(const uint2*)((const char*)sfT + cB + ccs * 8);
                        bbL[i] = qA.x; bbH[i] = qA.y;
                        bbL[i + 1] = qB.x; bbH[i + 1] = qB.y;
                    }
                }
#pragma unroll
                for (int k = 0; k < 8; ++k) { num0[k] = 0.f; num1[k] = 0.f; num2[k] = 0.f; den[k] = 0.f; }
            }

            int o0 = (361 * g) / OG, o1 = (361 * (g + 1)) / OG;
            for (int o = o0; o < o1; ++o) {
                int oy = o / 19, ox = o - oy * 19;
                int offy = oy - 9, offx = ox - 9;

                __syncthreads();   // prior pd reads of s_cs done
                if (act) {
                    float ring[9]; float s = 0.f;
                    if (rowOK) {
                        // interior rows: base row for iter i is (r0+i+9); single base
                        // VGPR + compile-time offset i*720 (<= 13680, fits imm).
                        const char* colp2 = (const char*)sfT + (ccs + offx) * 8
                                            + (offy + r0 + 9) * ROWB;
#pragma unroll
                        for (int i = 0; i < 20; ++i) {
                            uint2 q = *(const uint2*)(colp2 + i * ROWB);
                            float d2v = d2u(q.x, q.y, bbL[i], bbH[i]);
                            ring[i % 9] = d2v;
                            s += d2v;
                            if (i >= 8) {
                                if (i < nrows) cswb[(i - 8) * CSW] = s;
                                s -= ring[(i - 8) % 9];
                            }
                        }
                    } else {
                        // edge rows: staging clamp supplies clamp(clamp(base)+off)
                        const char* colp = (const char*)sfT + (ccs + offx) * 8 + offy * ROWB;
#pragma unroll
                        for (int i = 0; i < 20; ++i) {
                            int cb = (i & 1) ? (int)(cbyP[i >> 1] >> 16) : (int)(cbyP[i >> 1] & 0xffffu);
                            uint2 q = *(const uint2*)(colp + cb);
                            float d2v = d2u(q.x, q.y, bbL[i], bbH[i]);
                            ring[i % 9] = d2v;
                            s += d2v;
                            if (i >= 8) {
                                if (i < nrows) cswb[(i - 8) * CSW] = s;
                                s -= ring[(i - 8) % 9];
                            }
                        }
                    }
                }
                __syncthreads();

                // pd stage: sliding 9-wide row sums over cs
                float4 A = *(const float4*)(csr);
                float4 Bv = *(const float4*)(csr + 4);
                float4 Cv = *(const float4*)(csr + 8);
                float4 Dv = *(const float4*)(csr + 12);
                float w_[16] = { A.x, A.y, A.z, A.w, Bv.x, Bv.y, Bv.z, Bv.w,
                                 Cv.x, Cv.y, Cv.z, Cv.w, Dv.x, Dv.y, Dv.z, Dv.w };
                float pdv[8];
                pdv[0] = w_[0] + w_[1] + w_[2] + w_[3] + w_[4] + w_[5] + w_[6] + w_[7] + w_[8];
#pragma unroll
                for (int k = 1; k < 8; ++k) pdv[k] = pdv[k - 1] - w_[k - 1] + w_[k + 8];

                // wave-uniform: no clamping needed iff the whole tile+offset window
                // stays on-image.
                int safe = ((unsigned)(oyt + offy) <= (unsigned)(Hh - TH)) &
                           ((unsigned)(oxt + offx) <= (unsigned)(Ww - TW));
                if (safe) {
                    const float* xp = x + xbase + (offy * Ww + offx) * 3;
#pragma unroll
                    for (int k = 0; k < 8; ++k) {
                        float wgt = exp2fast(pdv[k] * mExp2);
                        num0[k] += wgt * xp[3 * k + 0];
                        num1[k] += wgt * xp[3 * k + 1];
                        num2[k] += wgt * xp[3 * k + 2];
                        den[k] += wgt;
                    }
                } else {
                    int ry = iclampi(oyt + ty + offy);
                    const float* xr = x + ry * (Ww * 3);
#pragma unroll
                    for (int k = 0; k < 8; ++k) {
                        float wgt = exp2fast(pdv[k] * mExp2);
                        int gx = iclampi(oxt + 8 * tx + k + offx);
                        const float* xq = xr + gx * 3;
                        num0[k] += wgt * xq[0];
                        num1[k] += wgt * xq[1];
                        num2[k] += wgt * xq[2];
                        den[k] += wgt;
                    }
                }
            }
        }

        // final flush
#pragma unroll
        for (int k = 0; k < 8; ++k) {
            int px = (oyt + ty) * Ww + oxt + 8 * tx + k;
            half4_t h = { (half_t)num0[k], (half_t)num1[k], (half_t)num2[k], (half_t)den[k] };
            part[(size_t)vslot * NPX + px] = h;
        }
    } else {
        // ---------------- GENERAL path (arbitrary patch filter) ----------------
        half_t* sd2g = su.d2g;
        const float isig2 = inv_sigma[0] * LOG2E;

        float num0[8], num1[8], num2[8], den[8];
        int bidx[12]; unsigned fbL[12], fbH[12];
        int cur_t = -1, oyt = 0, oxt = 0, vslot = 0;

        for (int it = b * IPB; it < b * IPB + IPB; ++it) {
            int t = it >> 6;
            int g = it & (OG - 1);

            if (t != cur_t) {
                if (cur_t >= 0) {
#pragma unroll
                    for (int k = 0; k < 8; ++k) {
                        int px = (oyt + ty) * Ww + oxt + 8 * tx + k;
                        half4_t h = { (half_t)num0[k], (half_t)num1[k], (half_t)num2[k], (half_t)den[k] };
                        part[(size_t)vslot * NPX + px] = h;
                    }
                }
                cur_t = t;
                int tyi = t / NTX;
                oyt = tyi * TH; oxt = (t - tyi * NTX) * TW;
                vslot = b - (OG * t) / IPB;

                __syncthreads();
                for (int e = tid; e < FHH * FHW; e += 256) {
                    int ly = e / FHW, lx = e - ly * FHW;
                    int gy = iclampi(oyt - 13 + ly), gx = iclampi(oxt - 13 + lx);
                    const float* fp = feat + (gy * Ww + gx) * 3;
                    sfT[e] = half4_t{ (half_t)fp[0], (half_t)fp[1], (half_t)fp[2], (half_t)0.f };
                }
                __syncthreads();

#pragma unroll
                for (int s = 0; s < 12; ++s) {
                    int e = tid + s * 256;
                    if (e < 40 * 72) {
                        int r = e / 72, cc = e - r * 72;
                        int ri = iclampi(oyt - 4 + r) - oyt + 13;
                        int ci = iclampi(oxt - 4 + cc) - oxt + 13;
                        bidx[s] = ri * FHW + ci;
                        uint2 q = *(const uint2*)&sfT[bidx[s]];
                        fbL[s] = q.x; fbH[s] = q.y;
                    } else { bidx[s] = 0; fbL[s] = 0; fbH[s] = 0; }
                }
#pragma unroll
                for (int k = 0; k < 8; ++k) { num0[k] = 0.f; num1[k] = 0.f; num2[k] = 0.f; den[k] = 0.f; }
            }

            int o0 = (361 * g) / OG, o1 = (361 * (g + 1)) / OG;
            for (int o = o0; o < o1; ++o) {
                int oy = o / 19, ox = o - oy * 19;
                int offy = oy - 9, offx = ox - 9;
                int du = offy * FHW + offx;

                __syncthreads();
#pragma unroll
                for (int s = 0; s < 12; ++s) {
                    int e = tid + s * 256;
                    if (e < 40 * 72) {
                        uint2 q = *(const uint2*)&sfT[bidx[s] + du];
                        sd2g[e] = (half_t)d2u(fbL[s], fbH[s], q.x, q.y);
                    }
                }
                __syncthreads();

                float pd[8];
#pragma unroll
                for (int k = 0; k < 8; ++k) pd[k] = 0.f;
#pragma unroll
                for (int i = 0; i < 9; ++i) {
                    const uint4* rp = (const uint4*)&sd2g[(ty + i) * 72 + 8 * tx];
                    uint4 Aq = rp[0], Bq = rp[1];
                    unsigned rr[8] = { Aq.x, Aq.y, Aq.z, Aq.w, Bq.x, Bq.y, Bq.z, Bq.w };
                    unsigned sh[7];
#pragma unroll
                    for (int m = 0; m < 7; ++m) sh[m] = __builtin_amdgcn_alignbit(rr[m + 1], rr[m], 16);
                    half2_t w0 = u2h(wpg[i * 6 + 0]), w1 = u2h(wpg[i * 6 + 1]);
                    half2_t w2 = u2h(wpg[i * 6 + 2]), w3 = u2h(wpg[i * 6 + 3]);
                    half2_t wtE = u2h(wpg[i * 6 + 4]), wtO = u2h(wpg[i * 6 + 5]);
#pragma unroll
                    for (int k = 0; k < 8; k += 2) {
                        int m = k >> 1;
                        float p = pd[k];
                        p = fdot2u(rr[m + 0], w0, p);
                        p = fdot2u(rr[m + 1], w1, p);
                        p = fdot2u(rr[m + 2], w2, p);
                        p = fdot2u(rr[m + 3], w3, p);
                        p = fdot2u(rr[m + 4], wtE, p);
                        pd[k] = p;
                        float q = pd[k + 1];
                        q = fdot2u(sh[m + 0], w0, q);
                        q = fdot2u(sh[m + 1], w1, q);
                        q = fdot2u(sh[m + 2], w2, q);
                        q = fdot2u(sh[m + 3], w3, q);
                        q = fdot2u(rr[m + 4], wtO, q);
                        pd[k + 1] = q;
                    }
                }

                int ry = iclampi(oyt + ty + offy);
                const float* xr = x + ry * (Ww * 3);
#pragma unroll
                for (int k = 0; k < 8; ++k) {
                    float wgt = exp2fast(-pd[k] * isig2);
                    int gx = iclampi(oxt + 8 * tx + k + offx);
                    const float* xq = xr + gx * 3;
                    num0[k] += wgt * xq[0];
                    num1[k] += wgt * xq[1];
                    num2[k] += wgt * xq[2];
                    den[k] += wgt;
                }
            }
        }

#pragma unroll
        for (int k = 0; k < 8; ++k) {
            int px = (oyt + ty) * Ww + oxt + 8 * tx + k;
            half4_t h = { (half_t)num0[k], (half_t)num1[k], (half_t)num2[k], (half_t)den[k] };
            part[(size_t)vslot * NPX + px] = h;
        }
    }
}

// ---------------- Kernel C: reduce visitor partials ----------------
__global__ __launch_bounds__(256) void k_reduce(const half4_t* __restrict__ part,
                                                float* __restrict__ out) {
    int px = blockIdx.x * 256 + threadIdx.x;
    if (px >= NPX) return;
    int y = px / Ww, xx = px - y * Ww;
    int t = (y / TH) * NTX + xx / TW;
    int bfirst = (OG * t) / IPB;
    int blast = (OG * t + OG - 1) / IPB;
    int nvis = blast - bfirst + 1;
    float n0 = 0.f, n1 = 0.f, n2 = 0.f, dd = 0.f;
#pragma unroll
    for (int v = 0; v < VMAX; ++v) {
        if (v < nvis) {
            half4_t h = part[(size_t)v * NPX + px];
            n0 += (float)h.x; n1 += (float)h.y; n2 += (float)h.z; dd += (float)h.w;
        }
    }
    float inv = 1.f / dd;
    out[px * 3 + 0] = n0 * inv;
    out[px * 3 + 1] = n1 * inv;
    out[px * 3 + 2] = n2 * inv;
}

extern "C" void kernel_launch(void* const* d_in, const int* in_sizes, int n_in,
                              void* d_out, int out_size, void* d_ws, size_t ws_size,
                              hipStream_t stream) {
    const float* x    = (const float*)d_in[0];
    const float* ff   = (const float*)d_in[1];
    const float* pf   = (const float*)d_in[2];
    const float* isig = (const float*)d_in[3];
    float* out = (float*)d_out;

    // ws layout: [feat NPX*3 f32][wpg+flag 256B][part VMAX*NPX half4]
    float* feat   = (float*)d_ws;
    unsigned* wpg = (unsigned*)((char*)d_ws + (size_t)NPX * 3 * 4);
    half4_t* part = (half4_t*)((char*)d_ws + (size_t)NPX * 3 * 4 + 256);

    k_feat<<<dim3(NPX / 256), 256, 0, stream>>>(x, ff, pf, feat, wpg);
    k_nlm<<<dim3(NBLK), 256, 0, stream>>>(x, feat, wpg, pf, isig, part);
    k_reduce<<<dim3((NPX + 255) / 256), 256, 0, stream>>>(part, out);
}